// Round 1
// baseline (5676.215 us; speedup 1.0000x reference)
//
#include <hip/hip_runtime.h>
#include <math.h>

// Problem constants (V2VNetFusion): N_AGENTS=2, B=4, C=64, H=200, W=352
#define HH 200
#define WW 352
#define HWSZ (HH*WW)          // 70400
#define CHW (64L*HWSZ)        // one (64,H,W) tensor = 4,505,600 elems

// Epilogue modes
enum { EPI_MSG=0, EPI_GATES=1, EPI_CAND=2 };

// Direct conv3x3, 'SAME' padding, input = virtual concat of up to 3
// 64-channel segments. Block tile: 64 out-channels x (4 rows x 16 cols).
// Thread (co = tid&63, r = tid>>6) computes 16 horizontally-contiguous
// pixels for one output channel. Input staged in LDS 4 channels at a time;
// within a wave all lanes share r -> s_in reads are broadcast (conflict-free);
// s_w packed stride-9 (gcd(9,32)=1 -> conflict-free).
template<int EPI>
__global__ __launch_bounds__(256)
void conv3x3_k(const float* __restrict__ seg0,
               const float* __restrict__ seg1,
               const float* __restrict__ seg2,
               int nseg, int ngroups,
               const float* __restrict__ wgt, int cin_total,
               const float* __restrict__ bias,
               const float* e_x0,   // MSG: x0 (batched)
               const float* e_h,    // GATES/CAND: previous h (nullptr => zeros)
               const float* e_upd,  // CAND: update gate
               float* out0,         // MSG: agg  GATES: rh  CAND: h_next
               float* out1)         // GATES: upd
{
    __shared__ float s_in[4][6][20];   // 4 ch x (4+2) rows x (16+2) cols (pad->20)
    __shared__ float s_w[4][64][9];    // 4 ch x 64 co x 9 taps

    const int tid = threadIdx.x;
    const int co  = tid & 63;
    const int r   = tid >> 6;

    const int z     = blockIdx.z;
    const int batch = z / ngroups;
    const int grp   = z - batch * ngroups;
    const int co_base = grp * 64;

    const long boff = (long)batch * CHW;   // batch stride for seg0/seg1 (msg conv)
    seg0 += boff;
    seg1 += boff;

    const int x0p = blockIdx.x * 16;
    const int y0  = blockIdx.y * 4;
    const int y   = y0 + r;

    float acc[16];
#pragma unroll
    for (int p=0;p<16;++p) acc[p]=0.f;

    const int cin = nseg * 64;
    for (int cc = 0; cc < cin; cc += 4) {
        const float* segp = (cc < 64) ? seg0 : ((cc < 128) ? seg1 : seg2);
        const int cbase = cc & 63;
        __syncthreads();
        // stage input: 4 ch x 6 rows x 18 cols, zero-padded at borders
        for (int i = tid; i < 4*6*18; i += 256) {
            int cl = i / 108; int rem = i - cl*108;
            int ry = rem / 18; int rx = rem - ry*18;
            int gy = y0 + ry - 1, gx = x0p + rx - 1;
            float v = 0.f;
            if (gy >= 0 && gy < HH && gx >= 0 && gx < WW)
                v = segp[(long)(cbase+cl)*HWSZ + gy*WW + gx];
            s_in[cl][ry][rx] = v;
        }
        // stage weights: 64 co x 4 ch x 9 taps (w layout: (Cout, Cin, 3, 3))
        for (int i = tid; i < 64*36; i += 256) {
            int col = i / 36; int rem = i - col*36;
            int cl = rem / 9; int k = rem - cl*9;
            s_w[cl][col][k] =
                wgt[((long)(co_base+col)*cin_total + (cc+cl))*9 + k];
        }
        __syncthreads();
#pragma unroll
        for (int cl = 0; cl < 4; ++cl) {
            float wr[9];
#pragma unroll
            for (int k=0;k<9;++k) wr[k] = s_w[cl][co][k];
#pragma unroll
            for (int ky=0; ky<3; ++ky) {
                float iv[18];
#pragma unroll
                for (int j=0;j<18;++j) iv[j] = s_in[cl][r+ky][j];
#pragma unroll
                for (int kx=0; kx<3; ++kx) {
                    const float w = wr[ky*3+kx];
#pragma unroll
                    for (int p=0;p<16;++p)
                        acc[p] = fmaf(w, iv[p+kx], acc[p]);
                }
            }
        }
    }

    const int co_g = co_base + co;
    const float b = bias[co_g];
    const long pixbase = (long)y*WW + x0p;

    if (EPI == EPI_MSG) {
        // agg = 0.5*(x0 + conv + bias)
        const float* x0ptr = e_x0 + boff + (long)co*HWSZ + pixbase;
        float* op = out0 + boff + (long)co*HWSZ + pixbase;
#pragma unroll
        for (int p=0;p<16;++p)
            op[p] = 0.5f*(x0ptr[p] + acc[p] + b);
    } else if (EPI == EPI_GATES) {
        // gates = sigmoid(conv+bias); co<64: rh = reset*h ; co>=64: upd = update
        if (co_g < 64) {
            const float* hp = e_h ? (e_h + (long)co_g*HWSZ + pixbase) : nullptr;
            float* op = out0 + (long)co_g*HWSZ + pixbase;
#pragma unroll
            for (int p=0;p<16;++p) {
                float g  = 1.f/(1.f+__expf(-(acc[p]+b)));
                float hv = hp ? hp[p] : 0.f;
                op[p] = g*hv;
            }
        } else {
            float* op = out1 + (long)(co_g-64)*HWSZ + pixbase;
#pragma unroll
            for (int p=0;p<16;++p)
                op[p] = 1.f/(1.f+__expf(-(acc[p]+b)));
        }
    } else {
        // cnm = tanh(conv+bias); h_next = (1-u)*h + u*cnm
        const float* hp = e_h ? (e_h + (long)co*HWSZ + pixbase) : nullptr;
        const float* up = e_upd + (long)co*HWSZ + pixbase;
        float* op = out0 + (long)co*HWSZ + pixbase;
#pragma unroll
        for (int p=0;p<16;++p) {
            float cnm = tanhf(acc[p]+b);
            float u   = up[p];
            float hv  = hp ? hp[p] : 0.f;
            op[p] = (1.f-u)*hv + u*cnm;
        }
    }
}

__global__ void copy_k(float* dst, const float* __restrict__ src, int n4)
{
    int i = blockIdx.x*blockDim.x + threadIdx.x;
    if (i < n4) ((float4*)dst)[i] = ((const float4*)src)[i];
}

// Dataflow:
//   msg conv (B=4 at once):  [x0 | x1] --conv--> agg = 0.5*(x0 + msg)   (agg aliased into d_out)
//   per step t (B acts as sequence length):
//     gates: [x0[t] | agg[t] | h] -> sigmoid -> rh = reset*h (ws), upd (ws)
//     cand : [x0[t] | agg[t] | rh] -> tanh -> h = (1-upd)*h + upd*cnm (ws)
//     copy : out[t] <- h   (clobbers agg[t], which is dead after step t)
// ws usage: rh + upd + hbuf = 3 * 18 MB = 54 MB.
extern "C" void kernel_launch(void* const* d_in, const int* in_sizes, int n_in,
                              void* d_out, int out_size, void* d_ws, size_t ws_size,
                              hipStream_t stream)
{
    const float* x       = (const float*)d_in[0];
    const float* msg_w   = (const float*)d_in[1];
    const float* msg_b   = (const float*)d_in[2];
    const float* gates_w = (const float*)d_in[3];
    const float* gates_b = (const float*)d_in[4];
    const float* can_w   = (const float*)d_in[5];
    const float* can_b   = (const float*)d_in[6];
    float* out = (float*)d_out;

    const float* x0 = x;                 // (4,64,H,W)
    const float* x1 = x + 4*CHW;         // (4,64,H,W)
    float* agg  = out;                   // (4,64,H,W) aliased into d_out
    float* rh   = (float*)d_ws;          // (64,H,W)
    float* upd  = rh  + CHW;             // (64,H,W)
    float* hbuf = upd + CHW;             // (64,H,W)

    dim3 blk(256);

    // message conv + avg-agg, all 4 batches (grid.z = batch)
    conv3x3_k<EPI_MSG><<<dim3(22,50,4), blk, 0, stream>>>(
        x0, x1, nullptr, /*nseg=*/2, /*ngroups=*/1, msg_w, 128, msg_b,
        x0, nullptr, nullptr, agg, nullptr);

    for (int t = 0; t < 4; ++t) {
        const float* xt = x0  + (long)t*CHW;
        const float* at = agg + (long)t*CHW;
        const float* h  = t ? hbuf : nullptr;   // h0 = 0 -> skip segment + treat as zeros
        // gates conv: 192 -> 128 (grid.z = co-group)
        conv3x3_k<EPI_GATES><<<dim3(22,50,2), blk, 0, stream>>>(
            xt, at, h, t ? 3 : 2, 2, gates_w, 192, gates_b,
            nullptr, h, nullptr, rh, upd);
        // candidate conv: 192 -> 64, fused GRU blend
        conv3x3_k<EPI_CAND><<<dim3(22,50,1), blk, 0, stream>>>(
            xt, at, rh, t ? 3 : 2, 1, can_w, 192, can_b,
            nullptr, h, upd, hbuf, nullptr);
        // out[t] = h  (separate kernel: avoids halo read/write race on d_out)
        copy_k<<<dim3((int)((CHW/4 + 255)/256)), blk, 0, stream>>>(
            out + (long)t*CHW, hbuf, (int)(CHW/4));
    }
}

// Round 2
// 2090.978 us; speedup vs baseline: 2.7146x; 2.7146x over previous
//
#include <hip/hip_runtime.h>
#include <hip/hip_bf16.h>
#include <math.h>

// V2VNetFusion on MI355X: bf16 MFMA implicit-GEMM conv3x3 with fp32 accum.
// Weights split into bf16 hi+lo (2 MFMAs) so conv error ~= input bf16
// quantization only (~4e-3), well under the 2e-2 threshold.
#define HH 200
#define WW 352
#define HWSZ (HH*WW)          // 70400
#define CHW (64L*HWSZ)        // one (64,H,W) tensor

enum { EPI_MSG=0, EPI_GATES=1, EPI_CAND=2 };

typedef __attribute__((ext_vector_type(8))) short bf16x8;   // 8 bf16 (4 VGPRs)
typedef __attribute__((ext_vector_type(4))) float f32x4;
typedef __attribute__((ext_vector_type(4))) unsigned int uint4v;

__device__ __forceinline__ unsigned short f2bf_rn(float f) {
    unsigned int u = __float_as_uint(f);
    unsigned int r = (u + 0x7fffu + ((u >> 16) & 1u)) >> 16;
    return (unsigned short)r;
}

// Prepack all conv weights into bf16 hi/lo planes in the exact LDS layout
// [cogrp][kb][sh(9)][hl(2)][co(32)][ch(32)], chunk = 18432 bf16 per (cogrp,kb).
//   msg:   2 cogrp x 4 kb ;  gates: 4 x 6 ;  cand: 2 x 6
__global__ void prepack_k(const float* __restrict__ mw,
                          const float* __restrict__ gw,
                          const float* __restrict__ cw,
                          unsigned short* __restrict__ pw)
{
    const int MSG_I = 2*4*9216;   // 73728 items
    const int GAT_I = 4*6*9216;   // 221184
    const int CAN_I = 2*6*9216;   // 110592
    int idx = blockIdx.x*256 + threadIdx.x;
    const float* w; int cin, nkb, rel; unsigned short* base;
    if (idx < MSG_I)              { w=mw; cin=128; nkb=4; rel=idx;              base=pw; }
    else if (idx < MSG_I+GAT_I)   { w=gw; cin=192; nkb=6; rel=idx-MSG_I;        base=pw+147456; }
    else if (idx < MSG_I+GAT_I+CAN_I) { w=cw; cin=192; nkb=6; rel=idx-MSG_I-GAT_I; base=pw+589824; }
    else return;
    int chunk = rel / 9216, r = rel - chunk*9216;
    int sh = r >> 10, r2 = r & 1023, co = r2 >> 5, ch = r2 & 31;
    int cogrp = chunk / nkb, kb = chunk - cogrp*nkb;
    float f = w[(((long)(cogrp*32+co))*cin + kb*32+ch)*9 + sh];
    unsigned short hi = f2bf_rn(f);
    float fl = f - __uint_as_float(((unsigned)hi) << 16);
    unsigned short lo = f2bf_rn(fl);
    unsigned short* cb = base + (size_t)chunk*18432;
    cb[(sh*2+0)*1024 + co*32 + ch] = hi;
    cb[(sh*2+1)*1024 + co*32 + ch] = lo;
}

// Block: 32 out-ch x (8 rows x 32 cols) pixels. 4 waves; wave w = rows 2w,2w+1.
// Wave tile: 32co x 64px = 2 co-frags x 4 px-frags of mfma_f32_16x16x32_bf16.
// K-loop: 32-channel blocks x 9 shifts; A = weights (hi+lo), B = input tile.
template<int EPI>
__global__ __launch_bounds__(256, 2)
void conv_mfma_k(const float* __restrict__ seg0,
                 const float* __restrict__ seg1,
                 const float* __restrict__ seg2,
                 int nkb, int nkb_stride, int ncogrp,
                 const unsigned short* __restrict__ pw,
                 const float* __restrict__ bias,
                 const float* __restrict__ e_x0,
                 const float* e_h,     // may alias out0 (cand in-place h)
                 const float* __restrict__ e_upd,
                 float* out0, float* out1)
{
    __shared__ unsigned short s_in[10*34*32];   // [row][col][ch] bf16, 21760 B
    __shared__ unsigned short s_w[9*2*32*32];   // [sh][hl][co][ch] bf16, 36864 B

    const int tid  = threadIdx.x;
    const int lane = tid & 63;
    const int wv   = tid >> 6;
    const int n16  = lane & 15;
    const int q    = lane >> 4;      // 0..3
    const int q8   = q * 8;

    const int z     = blockIdx.z;
    const int grp   = z % ncogrp;
    const int batch = z / ncogrp;
    const long boff = (long)batch * CHW;

    const float* segs[3];
    segs[0] = seg0 + boff;
    segs[1] = seg1 + boff;
    segs[2] = seg2;

    const int x0p = blockIdx.x * 32;
    const int y0  = blockIdx.y * 8;

    f32x4 acc[2][4];
#pragma unroll
    for (int cf=0; cf<2; ++cf)
#pragma unroll
        for (int p=0; p<4; ++p) acc[cf][p] = (f32x4){0.f,0.f,0.f,0.f};

    for (int kb = 0; kb < nkb; ++kb) {
        const float* seg = segs[kb >> 1];
        const int cofs = (kb & 1) * 32;
        __syncthreads();
        // ---- stage input slice: 10x34 halo x 32ch, fp32 -> bf16, [row][col][ch]
        for (int i = tid; i < 5440; i += 256) {
            const int cp  = i & 15;          // channel pair
            const int pos = i >> 4;          // 0..339
            const int row = pos / 34;
            const int col = pos - row*34;
            const int gy = y0 + row - 1;
            const int gx = x0p + col - 1;
            unsigned int pk = 0;
            if ((unsigned)gy < (unsigned)HH && (unsigned)gx < (unsigned)WW) {
                const float* p0 = seg + (long)(cofs + 2*cp)*HWSZ + (long)gy*WW + gx;
                pk = (unsigned)f2bf_rn(p0[0]) | ((unsigned)f2bf_rn(p0[HWSZ]) << 16);
            }
            *(unsigned int*)&s_in[pos*32 + 2*cp] = pk;
        }
        // ---- stage prepacked weights chunk (pure contiguous copy, 36864 B)
        const uint4v* wsrc = (const uint4v*)(pw + (size_t)(grp*nkb_stride + kb)*18432);
        uint4v* wdst = (uint4v*)s_w;
        for (int j = tid; j < 2304; j += 256) wdst[j] = wsrc[j];
        __syncthreads();
        // ---- compute: 9 shifts x (2 co-frags x {hi,lo}) x 4 px-frags
#pragma unroll
        for (int ky = 0; ky < 3; ++ky) {
#pragma unroll
            for (int kx = 0; kx < 3; ++kx) {
                bf16x8 bfr[4];
#pragma unroll
                for (int p = 0; p < 4; ++p) {
                    const int rl = 2*wv + (p >> 1) + ky;
                    const int cl = 16*(p & 1) + n16 + kx;
                    bfr[p] = *(const bf16x8*)&s_in[(rl*34 + cl)*32 + q8];
                }
                const int shb = (ky*3 + kx) * 2;
#pragma unroll
                for (int cf = 0; cf < 2; ++cf) {
                    bf16x8 ah = *(const bf16x8*)&s_w[((shb+0)*32 + cf*16 + n16)*32 + q8];
                    bf16x8 al = *(const bf16x8*)&s_w[((shb+1)*32 + cf*16 + n16)*32 + q8];
#pragma unroll
                    for (int p = 0; p < 4; ++p) {
                        acc[cf][p] = __builtin_amdgcn_mfma_f32_16x16x32_bf16(ah, bfr[p], acc[cf][p], 0, 0, 0);
                        acc[cf][p] = __builtin_amdgcn_mfma_f32_16x16x32_bf16(al, bfr[p], acc[cf][p], 0, 0, 0);
                    }
                }
            }
        }
    }

    // ---- epilogue. C/D layout: col(n)=lane&15 -> pixel, row=(lane>>4)*4+reg -> co
#pragma unroll
    for (int cf = 0; cf < 2; ++cf) {
        const int cobase = grp*32 + cf*16 + q*4;
#pragma unroll
        for (int p = 0; p < 4; ++p) {
            const int row = y0 + 2*wv + (p >> 1);
            const int col = x0p + 16*(p & 1) + n16;
            const long pix = (long)row*WW + col;
#pragma unroll
            for (int r = 0; r < 4; ++r) {
                const int co_g = cobase + r;
                const long o = (long)co_g*HWSZ + pix;
                const float v = acc[cf][p][r] + bias[co_g];
                if (EPI == EPI_MSG) {
                    out0[boff + o] = 0.5f*(e_x0[boff + o] + v);
                } else if (EPI == EPI_GATES) {
                    const float g = 1.f/(1.f + __expf(-v));
                    if (co_g < 64) {
                        const float hv = e_h ? e_h[o] : 0.f;
                        out0[o] = g * hv;                 // rh = reset*h
                    } else {
                        out1[o - 64L*HWSZ] = g;           // upd
                    }
                } else {
                    const float cnm = tanhf(v);
                    const float u  = e_upd[o];
                    const float hv = e_h ? e_h[o] : 0.f;
                    out0[o] = (1.f - u)*hv + u*cnm;       // h_next (in-place safe)
                }
            }
        }
    }
}

__global__ void copy_k(float* dst, const float* __restrict__ src, int n4)
{
    int i = blockIdx.x*blockDim.x + threadIdx.x;
    if (i < n4) ((float4*)dst)[i] = ((const float4*)src)[i];
}

// Dataflow (out aliased as agg; rh/upd/hbuf + packed weights in ws):
//   prepack -> msg conv (B=4) -> per t: gates conv -> cand conv -> copy out[t]<-h
extern "C" void kernel_launch(void* const* d_in, const int* in_sizes, int n_in,
                              void* d_out, int out_size, void* d_ws, size_t ws_size,
                              hipStream_t stream)
{
    const float* x       = (const float*)d_in[0];
    const float* msg_w   = (const float*)d_in[1];
    const float* msg_b   = (const float*)d_in[2];
    const float* gates_w = (const float*)d_in[3];
    const float* gates_b = (const float*)d_in[4];
    const float* can_w   = (const float*)d_in[5];
    const float* can_b   = (const float*)d_in[6];
    float* out = (float*)d_out;

    const float* x0 = x;
    const float* x1 = x + 4*CHW;
    float* agg  = out;                        // (4,64,H,W) aliased into d_out
    float* rh   = (float*)d_ws;               // (64,H,W)
    float* upd  = rh  + CHW;
    float* hbuf = upd + CHW;
    unsigned short* pw = (unsigned short*)((char*)d_ws + 3*CHW*sizeof(float));
    unsigned short* pw_msg = pw;              // 147456 bf16
    unsigned short* pw_gat = pw + 147456;     // 442368 bf16
    unsigned short* pw_can = pw + 589824;     // 221184 bf16

    prepack_k<<<dim3((405504 + 255)/256), dim3(256), 0, stream>>>(msg_w, gates_w, can_w, pw);

    // message conv + avg-agg: Cin=128 (x0|x1), Cout=64, 4 batches
    conv_mfma_k<EPI_MSG><<<dim3(11,25,8), dim3(256), 0, stream>>>(
        x0, x1, nullptr, 4, 4, 2, pw_msg, msg_b, x0, nullptr, nullptr, agg, nullptr);

    for (int t = 0; t < 4; ++t) {
        const float* xt = x0  + (long)t*CHW;
        const float* at = agg + (long)t*CHW;
        const float* h  = t ? hbuf : nullptr;     // h0 = 0 -> skip h segment
        // gates: Cin = [x | agg | h], Cout=128 -> sigmoid -> rh, upd
        conv_mfma_k<EPI_GATES><<<dim3(11,25,4), dim3(256), 0, stream>>>(
            xt, at, h, t ? 6 : 4, 6, 4, pw_gat, gates_b, nullptr, h, nullptr, rh, upd);
        // cand: Cin = [x | agg | rh], Cout=64 -> tanh -> h = (1-u)*h + u*cnm
        conv_mfma_k<EPI_CAND><<<dim3(11,25,2), dim3(256), 0, stream>>>(
            xt, at, rh, t ? 6 : 4, 6, 2, pw_can, can_b, nullptr, h, upd, hbuf, nullptr);
        copy_k<<<dim3(4400), dim3(256), 0, stream>>>(out + (long)t*CHW, hbuf, (int)(CHW/4));
    }
}

// Round 3
// 888.993 us; speedup vs baseline: 6.3850x; 2.3521x over previous
//
#include <hip/hip_runtime.h>
#include <hip/hip_bf16.h>
#include <math.h>

// V2VNetFusion on MI355X: bf16 MFMA implicit-GEMM conv3x3, fp32 accum,
// weights split bf16 hi+lo. Round 3: all conv inputs kept in pixel-
// interleaved bf16 [half][pix][32ch] so conv staging is contiguous b128
// copies; epilogues emit bf16-interleaved outputs directly.
#define HH 200
#define WW 352
#define HWSZ (HH*WW)          // 70400
#define CHW (64L*HWSZ)        // one (64,H,W) tensor, elems

enum { EPI_MSG=0, EPI_GATES=1, EPI_CAND=2 };

typedef __attribute__((ext_vector_type(8))) short bf16x8;
typedef __attribute__((ext_vector_type(4))) float f32x4;
typedef __attribute__((ext_vector_type(4))) unsigned int uint4v;
typedef __attribute__((ext_vector_type(4))) unsigned short ushort4v;

__device__ __forceinline__ unsigned short f2bf_rn(float f) {
    unsigned int u = __float_as_uint(f);
    unsigned int r = (u + 0x7fffu + ((u >> 16) & 1u)) >> 16;
    return (unsigned short)r;
}

// Prepack conv weights into bf16 hi/lo planes, LDS-ready layout
// [cogrp][kb][sh(9)][hl(2)][co(32)][ch(32)]; 18432 bf16 per (cogrp,kb).
//   msg: 2 cogrp x 4 kb ; gates: 4 x 6 ; cand: 2 x 6    (unchanged from R2)
__global__ void prepack_k(const float* __restrict__ mw,
                          const float* __restrict__ gw,
                          const float* __restrict__ cw,
                          unsigned short* __restrict__ pw)
{
    const int MSG_I = 2*4*9216;
    const int GAT_I = 4*6*9216;
    const int CAN_I = 2*6*9216;
    int idx = blockIdx.x*256 + threadIdx.x;
    const float* w; int cin, nkb, rel; unsigned short* base;
    if (idx < MSG_I)              { w=mw; cin=128; nkb=4; rel=idx;              base=pw; }
    else if (idx < MSG_I+GAT_I)   { w=gw; cin=192; nkb=6; rel=idx-MSG_I;        base=pw+147456; }
    else if (idx < MSG_I+GAT_I+CAN_I) { w=cw; cin=192; nkb=6; rel=idx-MSG_I-GAT_I; base=pw+589824; }
    else return;
    int chunk = rel / 9216, r = rel - chunk*9216;
    int sh = r >> 10, r2 = r & 1023, co = r2 >> 5, ch = r2 & 31;
    int cogrp = chunk / nkb, kb = chunk - cogrp*nkb;
    float f = w[(((long)(cogrp*32+co))*cin + kb*32+ch)*9 + sh];
    unsigned short hi = f2bf_rn(f);
    float fl = f - __uint_as_float(((unsigned)hi) << 16);
    unsigned short lo = f2bf_rn(fl);
    unsigned short* cb = base + (size_t)chunk*18432;
    cb[(sh*2+0)*1024 + co*32 + ch] = hi;
    cb[(sh*2+1)*1024 + co*32 + ch] = lo;
}

// Convert x[t] (agent0+agent1) fp32 planar -> bf16 interleaved [2][pix][32].
// Coalesced: lane group (16 cp) covers one pixel's 64B; float4 reads.
__global__ void convert_x_k(const float* __restrict__ xt0,
                            const float* __restrict__ xt1,
                            unsigned short* __restrict__ xb0,
                            unsigned short* __restrict__ xb1)
{
    int idx = blockIdx.x*256 + threadIdx.x;        // 1,126,400 total
    int cp   = idx & 15;
    int rest = idx >> 4;                            // 0..70399
    int px4  = rest % 17600;
    int r2   = rest / 17600;                        // 0..3
    int hb  = r2 & 1, img = r2 >> 1;
    const float* src = (img ? xt1 : xt0) + (size_t)(hb*32 + 2*cp)*HWSZ + px4*4;
    float4 a = *(const float4*)src;
    float4 b = *(const float4*)(src + HWSZ);
    unsigned int* dst = (unsigned int*)((img ? xb1 : xb0) + (size_t)hb*HWSZ*32)
                        + px4*64 + cp;
    dst[0]  = (unsigned)f2bf_rn(a.x) | ((unsigned)f2bf_rn(b.x) << 16);
    dst[16] = (unsigned)f2bf_rn(a.y) | ((unsigned)f2bf_rn(b.y) << 16);
    dst[32] = (unsigned)f2bf_rn(a.z) | ((unsigned)f2bf_rn(b.z) << 16);
    dst[48] = (unsigned)f2bf_rn(a.w) | ((unsigned)f2bf_rn(b.w) << 16);
}

// Block: 32 out-ch x (16 rows x 32 cols), 512 thr = 8 waves; wave w = rows
// 2w,2w+1 (64 px). LDS: input [18][34][32] bf16 XOR-swizzled + weights
// [9][2][32][32] = 76032 B -> 2 blocks/CU (16 waves/CU).
// Inputs are bf16 interleaved [half][pix][32]; staging = contiguous b128.
template<int EPI>
__global__ __launch_bounds__(512, 4)
void conv_mfma_k(const unsigned short* __restrict__ seg0b,
                 const unsigned short* __restrict__ seg1b,
                 const unsigned short* __restrict__ seg2b,
                 int nkb, int nkb_stride,
                 const unsigned short* __restrict__ pw,
                 const float* __restrict__ bias,
                 const float* __restrict__ e_x0,  // MSG: x[t] fp32 planar
                 const float* e_h,                // fp32 planar h_{t-1} (null @ t=0)
                 const float* __restrict__ e_upd, // CAND: upd fp32 planar
                 float* out_f,                    // GATES: upd  CAND: out[t]
                 unsigned short* out_b)           // MSG: aggb GATES: rhb CAND: hb
{
    __shared__ unsigned short s_in[612*32];   // [pos=row*34+col][32ch] 39168 B
    __shared__ unsigned short s_w[9*2*32*32]; // 36864 B

    const int tid  = threadIdx.x;
    const int lane = tid & 63;
    const int wv   = tid >> 6;
    const int n16  = lane & 15;
    const int q    = lane >> 4;
    const int q8   = q * 8;

    const int grp = blockIdx.z;
    const int x0p = blockIdx.x * 32;
    const int y0  = blockIdx.y * 16;

    f32x4 acc[2][4];
#pragma unroll
    for (int cf=0; cf<2; ++cf)
#pragma unroll
        for (int p=0; p<4; ++p) acc[cf][p] = (f32x4){0.f,0.f,0.f,0.f};

    for (int kb = 0; kb < nkb; ++kb) {
        const unsigned short* src =
            ((kb < 2) ? seg0b : (kb < 4) ? seg1b : seg2b) + (size_t)(kb & 1)*HWSZ*32;
        __syncthreads();
        // ---- input tile: 18 rows x 34 cols x 32 ch = 2448 16B-granules
        for (int i = tid; i < 2448; i += 512) {
            const int pos = i >> 2;          // 0..611
            const int g   = i & 3;
            const int row = pos / 34;
            const int col = pos - row*34;
            const int gy = y0 + row - 1;
            const int gx = x0p + col - 1;
            uint4v v = (uint4v){0u,0u,0u,0u};
            if ((unsigned)gy < (unsigned)HH && (unsigned)gx < (unsigned)WW)
                v = *(const uint4v*)(src + ((size_t)(gy*WW + gx) << 5) + (g << 3));
            const int sw = (g ^ pos ^ (pos >> 2)) & 3;
            *(uint4v*)&s_in[(pos << 5) + (sw << 3)] = v;
        }
        // ---- weights chunk: contiguous 36864 B copy
        const uint4v* wsrc = (const uint4v*)(pw + (size_t)(grp*nkb_stride + kb)*18432);
        uint4v* wdst = (uint4v*)s_w;
        for (int j = tid; j < 2304; j += 512) wdst[j] = wsrc[j];
        __syncthreads();
        // ---- 9 shifts x (2 co-frags x {hi,lo}) x 4 px-frags
#pragma unroll
        for (int ky = 0; ky < 3; ++ky) {
#pragma unroll
            for (int kx = 0; kx < 3; ++kx) {
                bf16x8 bfr[4];
#pragma unroll
                for (int p = 0; p < 4; ++p) {
                    const int rl = 2*wv + (p >> 1) + ky;       // 0..17
                    const int cl = 16*(p & 1) + n16 + kx;      // 0..33
                    const int pos = rl*34 + cl;
                    const int sw = (q ^ pos ^ (pos >> 2)) & 3;
                    bfr[p] = *(const bf16x8*)&s_in[(pos << 5) + (sw << 3)];
                }
                const int shb = (ky*3 + kx) * 2;
#pragma unroll
                for (int cf = 0; cf < 2; ++cf) {
                    bf16x8 ah = *(const bf16x8*)&s_w[((shb+0)*32 + cf*16 + n16)*32 + q8];
                    bf16x8 al = *(const bf16x8*)&s_w[((shb+1)*32 + cf*16 + n16)*32 + q8];
#pragma unroll
                    for (int p = 0; p < 4; ++p) {
                        acc[cf][p] = __builtin_amdgcn_mfma_f32_16x16x32_bf16(ah, bfr[p], acc[cf][p], 0, 0, 0);
                        acc[cf][p] = __builtin_amdgcn_mfma_f32_16x16x32_bf16(al, bfr[p], acc[cf][p], 0, 0, 0);
                    }
                }
            }
        }
    }

    // ---- epilogue. C/D: pixel = lane&15, co = (lane>>4)*4 + reg
#pragma unroll
    for (int cf = 0; cf < 2; ++cf) {
        const int cobase = grp*32 + cf*16 + q*4;   // global co of reg 0
        const int cmod   = cf*16 + q*4;            // co within 32-plane
#pragma unroll
        for (int p = 0; p < 4; ++p) {
            const int row = y0 + 2*wv + (p >> 1);
            const int col = x0p + 16*(p & 1) + n16;
            if (row >= HH) continue;
            const long pix = (long)row*WW + col;
            float v[4];
#pragma unroll
            for (int r = 0; r < 4; ++r) v[r] = acc[cf][p][r] + bias[cobase + r];

            if (EPI == EPI_MSG) {
                ushort4v s;
#pragma unroll
                for (int r = 0; r < 4; ++r) {
                    float m = 0.5f*(e_x0[(long)(cobase+r)*HWSZ + pix] + v[r]);
                    s[r] = f2bf_rn(m);
                }
                *(ushort4v*)&out_b[((size_t)grp*HWSZ + pix)*32 + cmod] = s;
            } else if (EPI == EPI_GATES) {
                if (grp < 2) {   // reset gate -> rh = sigmoid * h  (bf16 interleaved)
                    ushort4v s;
#pragma unroll
                    for (int r = 0; r < 4; ++r) {
                        float g  = 1.f/(1.f + __expf(-v[r]));
                        float hv = e_h ? e_h[(long)(cobase+r)*HWSZ + pix] : 0.f;
                        s[r] = f2bf_rn(g*hv);
                    }
                    *(ushort4v*)&out_b[((size_t)grp*HWSZ + pix)*32 + cmod] = s;
                } else {         // update gate -> upd fp32 planar
#pragma unroll
                    for (int r = 0; r < 4; ++r)
                        out_f[(long)(cobase-64+r)*HWSZ + pix] = 1.f/(1.f + __expf(-v[r]));
                }
            } else {             // CAND: h_next fp32 planar + bf16 interleaved
                ushort4v s;
#pragma unroll
                for (int r = 0; r < 4; ++r) {
                    float cnm = tanhf(v[r]);
                    float u   = e_upd[(long)(cobase+r)*HWSZ + pix];
                    float hv  = e_h ? e_h[(long)(cobase+r)*HWSZ + pix] : 0.f;
                    float hn  = (1.f - u)*hv + u*cnm;
                    out_f[(long)(cobase+r)*HWSZ + pix] = hn;
                    s[r] = f2bf_rn(hn);
                }
                *(ushort4v*)&out_b[((size_t)grp*HWSZ + pix)*32 + cmod] = s;
            }
        }
    }
}

// ws layout (bytes): xb0 9.0M | xb1/rhb 9.0M | aggb 9.0M | hb 9.0M |
//                    upd fp32 18.0M | pw 1.62M   == 55.69 MB (same as R2)
// Flow per step t: convert x -> msg (aggb) -> gates (rhb, upd) -> cand (out[t], hb)
extern "C" void kernel_launch(void* const* d_in, const int* in_sizes, int n_in,
                              void* d_out, int out_size, void* d_ws, size_t ws_size,
                              hipStream_t stream)
{
    const float* x       = (const float*)d_in[0];
    const float* msg_w   = (const float*)d_in[1];
    const float* msg_b   = (const float*)d_in[2];
    const float* gates_w = (const float*)d_in[3];
    const float* gates_b = (const float*)d_in[4];
    const float* can_w   = (const float*)d_in[5];
    const float* can_b   = (const float*)d_in[6];
    float* out = (float*)d_out;

    unsigned short* W    = (unsigned short*)d_ws;
    unsigned short* xb0  = W;                 // [2][HWSZ][32]
    unsigned short* xb1  = W + CHW;           // shared with rhb (disjoint lifetimes)
    unsigned short* aggb = W + 2*CHW;
    unsigned short* hb   = W + 3*CHW;
    float*          upd  = (float*)(W + 4*CHW);
    unsigned short* pw   = (unsigned short*)(upd + CHW);
    unsigned short* pw_msg = pw;
    unsigned short* pw_gat = pw + 147456;
    unsigned short* pw_can = pw + 589824;
    unsigned short* rhb  = xb1;

    prepack_k<<<dim3(1584), dim3(256), 0, stream>>>(msg_w, gates_w, can_w, pw);

    for (int t = 0; t < 4; ++t) {
        const float* xt = x + (long)t*CHW;
        const float* hprev = t ? (out + (long)(t-1)*CHW) : nullptr;

        convert_x_k<<<dim3(4400), dim3(256), 0, stream>>>(
            xt, x + (long)(4+t)*CHW, xb0, xb1);

        // msg: Cin=[x0|x1] (4 kb), Cout=64 (2 cogrp) -> aggb
        conv_mfma_k<EPI_MSG><<<dim3(11,13,2), dim3(512), 0, stream>>>(
            xb0, xb1, nullptr, 4, 4, pw_msg, msg_b,
            xt, nullptr, nullptr, nullptr, aggb);

        // gates: Cin=[x|agg|h] (6/4 kb), Cout=128 (4 cogrp) -> rhb, upd
        conv_mfma_k<EPI_GATES><<<dim3(11,13,4), dim3(512), 0, stream>>>(
            xb0, aggb, hb, t ? 6 : 4, 6, pw_gat, gates_b,
            nullptr, hprev, nullptr, upd, rhb);

        // cand: Cin=[x|agg|rh] (6/4 kb), Cout=64 (2 cogrp) -> out[t], hb
        conv_mfma_k<EPI_CAND><<<dim3(11,13,2), dim3(512), 0, stream>>>(
            xb0, aggb, rhb, t ? 6 : 4, 6, pw_can, can_b,
            nullptr, hprev, upd, out + (long)t*CHW, hb);
    }
}

// Round 4
// 706.027 us; speedup vs baseline: 8.0397x; 1.2591x over previous
//
#include <hip/hip_runtime.h>
#include <math.h>
#include <string.h>

// V2VNetFusion on MI355X, round 4: f16 MFMA implicit-GEMM conv3x3 (fp32
// accum). f16 (10 mantissa bits) is accurate enough to drop the bf16
// hi/lo weight split -> half the MFMA work of round 3. All conv inputs /
// GRU state kept in pixel-interleaved f16 [half][pix][32ch]; staging is
// contiguous b128 copies. convert + msg batched across all 4 timesteps;
// xb1 / aggb alias dead regions of d_out to bound ws at ~73 MB.
#define HH 200
#define WW 352
#define HWSZ (HH*WW)          // 70400
#define CHW (64L*HWSZ)        // one (64,H,W) tensor, elems

enum { EPI_MSG=0, EPI_GATES=1, EPI_CAND=2 };

typedef __attribute__((ext_vector_type(8))) _Float16 f16x8;
typedef __attribute__((ext_vector_type(4))) float f32x4;
typedef __attribute__((ext_vector_type(4))) unsigned int uint4v;
typedef __attribute__((ext_vector_type(4))) unsigned short ushort4v;

__device__ __forceinline__ unsigned short f2h(float f) {
    _Float16 h = (_Float16)f;                    // v_cvt_f16_f32 (RTE)
    return __builtin_bit_cast(unsigned short, h);
}
__device__ __forceinline__ float h2f(unsigned short u) {
    return (float)__builtin_bit_cast(_Float16, u);
}

// Prepack conv weights to f16, LDS-ready lane-major layout:
// [cogrp][kb][sh(9)][cf(2)][lane(64)][8ch]; 9216 f16 per (cogrp,kb) chunk.
// lane = q*16+n16 -> co = cf*16+n16, ch = q*8+j.   msg: 2x4, gates: 4x6, cand: 2x6
__global__ void prepack_k(const float* __restrict__ mw,
                          const float* __restrict__ gw,
                          const float* __restrict__ cw,
                          unsigned short* __restrict__ pw)
{
    const int MSG_I = 2*4*9216;
    const int GAT_I = 4*6*9216;
    const int CAN_I = 2*6*9216;
    int idx = blockIdx.x*256 + threadIdx.x;
    const float* w; int cin, nkb, rel; unsigned short* base;
    if (idx < MSG_I)              { w=mw; cin=128; nkb=4; rel=idx;              base=pw; }
    else if (idx < MSG_I+GAT_I)   { w=gw; cin=192; nkb=6; rel=idx-MSG_I;        base=pw+73728; }
    else if (idx < MSG_I+GAT_I+CAN_I) { w=cw; cin=192; nkb=6; rel=idx-MSG_I-GAT_I; base=pw+294912; }
    else return;
    int chunk = rel / 9216, r = rel - chunk*9216;
    int j = r & 7, lane = (r >> 3) & 63, cfsh = r >> 9;
    int cf = cfsh & 1, sh = cfsh >> 1;
    int q = lane >> 4, n16 = lane & 15;
    int co = cf*16 + n16, ch = q*8 + j;
    int cogrp = chunk / nkb, kb = chunk - cogrp*nkb;
    float f = w[(((long)(cogrp*32+co))*cin + kb*32+ch)*9 + sh];
    base[(size_t)chunk*9216 + r] = f2h(f);
}

// Convert x (2 agents x 4 t) fp32 planar -> f16 interleaved [t][half][pix][32].
// xb1 goes into d_out[0..1] region (dead until step 0 writes out[0]).
__global__ void convert_all_k(const float* __restrict__ x,
                              unsigned short* __restrict__ xb0_all,
                              unsigned short* __restrict__ xb1_all)
{
    int idx = blockIdx.x*256 + threadIdx.x;      // 4,505,600 total
    int cp   = idx & 15;
    int rest = idx >> 4;
    int px4  = rest % 17600;
    int r2   = rest / 17600;                      // 0..15
    int hb = r2 & 1, ag = (r2 >> 1) & 1, t = r2 >> 2;
    const float* src = x + ((size_t)(ag*4 + t))*CHW
                         + (size_t)(hb*32 + 2*cp)*HWSZ + (size_t)px4*4;
    float4 a = *(const float4*)src;
    float4 b = *(const float4*)(src + HWSZ);
    unsigned int* dst = (unsigned int*)((ag ? xb1_all : xb0_all)
                        + (size_t)t*CHW + (size_t)hb*HWSZ*32) + (size_t)px4*64 + cp;
    dst[0]  = (unsigned)f2h(a.x) | ((unsigned)f2h(b.x) << 16);
    dst[16] = (unsigned)f2h(a.y) | ((unsigned)f2h(b.y) << 16);
    dst[32] = (unsigned)f2h(a.z) | ((unsigned)f2h(b.z) << 16);
    dst[48] = (unsigned)f2h(a.w) | ((unsigned)f2h(b.w) << 16);
}

// Block: 32 out-ch x (16 rows x 32 cols), 512 thr = 8 waves; wave w = rows
// 2w,2w+1. LDS: input [18][34][32] f16 XOR-swizzled (39168 B) + weights
// [9][2][64][8] (18432 B) = 57.6 KB -> 2 blocks/CU.
template<int EPI>
__global__ __launch_bounds__(512, 4)
void conv_mfma_k(const unsigned short* __restrict__ seg0b,
                 const unsigned short* __restrict__ seg1b,
                 const unsigned short* __restrict__ seg2b,
                 int nkb, int nkb_stride,
                 const unsigned short* __restrict__ pw,
                 const float* __restrict__ bias,
                 const unsigned short* e_hb,     // f16 interl. h_{t-1} (null @t=0)
                 const unsigned short* __restrict__ e_updb, // CAND: upd f16 interl.
                 float* out_f,                   // CAND: out[t] fp32 planar
                 unsigned short* out_b,          // MSG: aggb(t<3) GATES: rhb CAND: hb
                 unsigned short* out_b2)         // MSG: aggb3    GATES: updb
{
    __shared__ unsigned short s_in[612*32];    // [pos=row*34+col][32ch] 39168 B
    __shared__ unsigned short s_w[9*2*64*8];   // [sh][cf][lane][8]     18432 B

    const int tid  = threadIdx.x;
    const int lane = tid & 63;
    const int wv   = tid >> 6;
    const int n16  = lane & 15;
    const int q    = lane >> 4;
    const int q8   = q * 8;

    const int z = blockIdx.z;
    int grp, ts = 0;
    if (EPI == EPI_MSG) { ts = z >> 1; grp = z & 1; } else grp = z;

    const unsigned short* s0 = seg0b + (EPI==EPI_MSG ? (size_t)ts*CHW : 0);
    const unsigned short* s1 = seg1b + (EPI==EPI_MSG ? (size_t)ts*CHW : 0);
    unsigned short* ob = out_b;
    if (EPI == EPI_MSG) ob = (ts < 3) ? out_b + (size_t)ts*CHW : out_b2;

    const int x0p = blockIdx.x * 32;
    const int y0  = blockIdx.y * 16;

    f32x4 acc[2][4];
#pragma unroll
    for (int cf=0; cf<2; ++cf)
#pragma unroll
        for (int p=0; p<4; ++p) acc[cf][p] = (f32x4){0.f,0.f,0.f,0.f};

    for (int kb = 0; kb < nkb; ++kb) {
        const unsigned short* src =
            ((kb < 2) ? s0 : (kb < 4) ? s1 : seg2b) + (size_t)(kb & 1)*HWSZ*32;
        __syncthreads();
        // ---- input tile: 18 rows x 34 cols x 32 ch = 2448 16B-granules
        for (int i = tid; i < 2448; i += 512) {
            const int pos = i >> 2;
            const int g   = i & 3;
            const int row = pos / 34;
            const int col = pos - row*34;
            const int gy = y0 + row - 1;
            const int gx = x0p + col - 1;
            uint4v v = (uint4v){0u,0u,0u,0u};
            if ((unsigned)gy < (unsigned)HH && (unsigned)gx < (unsigned)WW)
                v = *(const uint4v*)(src + ((size_t)(gy*WW + gx) << 5) + (g << 3));
            const int sw = (g ^ pos ^ (pos >> 2)) & 3;
            *(uint4v*)&s_in[(pos << 5) + (sw << 3)] = v;
        }
        // ---- weights chunk: contiguous 18432 B copy
        const uint4v* wsrc = (const uint4v*)(pw + (size_t)(grp*nkb_stride + kb)*9216);
        uint4v* wdst = (uint4v*)s_w;
        for (int j = tid; j < 1152; j += 512) wdst[j] = wsrc[j];
        __syncthreads();
        // ---- 9 shifts x 2 co-frags x 4 px-frags (single f16 MFMA each)
#pragma unroll
        for (int ky = 0; ky < 3; ++ky) {
#pragma unroll
            for (int kx = 0; kx < 3; ++kx) {
                bf16x8_dummy: ;
                f16x8 bfr[4];
#pragma unroll
                for (int p = 0; p < 4; ++p) {
                    const int rl = 2*wv + (p >> 1) + ky;
                    const int cl = 16*(p & 1) + n16 + kx;
                    const int pos = rl*34 + cl;
                    const int sw = (q ^ pos ^ (pos >> 2)) & 3;
                    bfr[p] = *(const f16x8*)&s_in[(pos << 5) + (sw << 3)];
                }
                const int sh = ky*3 + kx;
#pragma unroll
                for (int cf = 0; cf < 2; ++cf) {
                    f16x8 aw = *(const f16x8*)&s_w[((sh*2 + cf)*64 + lane)*8];
#pragma unroll
                    for (int p = 0; p < 4; ++p)
                        acc[cf][p] = __builtin_amdgcn_mfma_f32_16x16x32_f16(aw, bfr[p], acc[cf][p], 0, 0, 0);
                }
            }
        }
    }

    // ---- epilogue. C/D: pixel = lane&15, co = (lane>>4)*4 + reg
#pragma unroll
    for (int cf = 0; cf < 2; ++cf) {
        const int cobase = grp*32 + cf*16 + q*4;   // global co of reg 0
        const int cmod   = cf*16 + q*4;            // co within 32-plane
#pragma unroll
        for (int p = 0; p < 4; ++p) {
            const int row = y0 + 2*wv + (p >> 1);
            const int col = x0p + 16*(p & 1) + n16;
            if (row >= HH) continue;
            const long pix = (long)row*WW + col;
            const size_t iidx = (((size_t)grp*HWSZ + pix) << 5) + cmod;
            float v[4];
#pragma unroll
            for (int r = 0; r < 4; ++r) v[r] = acc[cf][p][r] + bias[cobase + r];

            if (EPI == EPI_MSG) {
                ushort4v xv = *(const ushort4v*)&s0[iidx];
                ushort4v s;
#pragma unroll
                for (int r = 0; r < 4; ++r)
                    s[r] = f2h(0.5f*(h2f(xv[r]) + v[r]));
                *(ushort4v*)&ob[iidx] = s;
            } else if (EPI == EPI_GATES) {
                if (grp < 2) {   // reset -> rh = sigmoid * h (f16 interleaved)
                    ushort4v hv = e_hb ? *(const ushort4v*)&e_hb[iidx]
                                       : (ushort4v){0,0,0,0};
                    ushort4v s;
#pragma unroll
                    for (int r = 0; r < 4; ++r) {
                        float g = 1.f/(1.f + __expf(-v[r]));
                        s[r] = f2h(g * h2f(hv[r]));
                    }
                    *(ushort4v*)&out_b[iidx] = s;
                } else {         // update -> updb (f16 interleaved)
                    const size_t uidx = ((((size_t)(grp-2))*HWSZ + pix) << 5) + cmod;
                    ushort4v s;
#pragma unroll
                    for (int r = 0; r < 4; ++r)
                        s[r] = f2h(1.f/(1.f + __expf(-v[r])));
                    *(ushort4v*)&out_b2[uidx] = s;
                }
            } else {             // CAND: h_next -> out fp32 planar + hb f16
                ushort4v uv = *(const ushort4v*)&e_updb[iidx];
                ushort4v hv = e_hb ? *(const ushort4v*)&e_hb[iidx]
                                   : (ushort4v){0,0,0,0};
                ushort4v s;
#pragma unroll
                for (int r = 0; r < 4; ++r) {
                    float cnm = tanhf(v[r]);
                    float u   = h2f(uv[r]);
                    float hn  = (1.f - u)*h2f(hv[r]) + u*cnm;
                    out_f[(long)(cobase+r)*HWSZ + pix] = hn;
                    s[r] = f2h(hn);
                }
                *(ushort4v*)&out_b[iidx] = s;
            }
        }
    }
}

// ws (u16 units): xb0_all 4C | aggb3 C | rhb C | updb C | hb C | pw 405504
//   = 72.9 MB.   d_out aliases: xb1_all = out[0..1] (dead until step 0),
//   aggb[0..2] = out[2..3] (aggb[t] dead before its region is written).
extern "C" void kernel_launch(void* const* d_in, const int* in_sizes, int n_in,
                              void* d_out, int out_size, void* d_ws, size_t ws_size,
                              hipStream_t stream)
{
    const float* x       = (const float*)d_in[0];
    const float* msg_w   = (const float*)d_in[1];
    const float* msg_b   = (const float*)d_in[2];
    const float* gates_w = (const float*)d_in[3];
    const float* gates_b = (const float*)d_in[4];
    const float* can_w   = (const float*)d_in[5];
    const float* can_b   = (const float*)d_in[6];
    float* out = (float*)d_out;

    unsigned short* W       = (unsigned short*)d_ws;
    unsigned short* xb0_all = W;                  // [4][2][HWSZ][32]
    unsigned short* aggb3   = W + 4*CHW;
    unsigned short* rhb     = W + 5*CHW;
    unsigned short* updb    = W + 6*CHW;
    unsigned short* hb      = W + 7*CHW;
    unsigned short* pw      = W + 8*CHW;          // 405504 u16
    unsigned short* pw_msg  = pw;
    unsigned short* pw_gat  = pw + 73728;
    unsigned short* pw_can  = pw + 294912;

    unsigned short* outU16   = (unsigned short*)d_out;
    unsigned short* xb1_all  = outU16;            // 4*CHW u16 = out[0..1]
    unsigned short* aggbase  = outU16 + 4*CHW;    // aggb[0..2] = out[2..3]

    prepack_k<<<dim3(1584), dim3(256), 0, stream>>>(msg_w, gates_w, can_w, pw);
    convert_all_k<<<dim3(17600), dim3(256), 0, stream>>>(x, xb0_all, xb1_all);

    // msg for all 4 t in one dispatch: Cin=[x0|x1], Cout=64 -> aggb[t]
    conv_mfma_k<EPI_MSG><<<dim3(11,13,8), dim3(512), 0, stream>>>(
        xb0_all, xb1_all, nullptr, 4, 4, pw_msg, msg_b,
        nullptr, nullptr, nullptr, aggbase, aggb3);

    for (int t = 0; t < 4; ++t) {
        const unsigned short* xt  = xb0_all + (size_t)t*CHW;
        const unsigned short* agt = (t < 3) ? aggbase + (size_t)t*CHW : aggb3;
        const unsigned short* hprev = t ? hb : nullptr;

        // gates: Cin=[x|agg|h], Cout=128 -> rhb, updb
        conv_mfma_k<EPI_GATES><<<dim3(11,13,4), dim3(512), 0, stream>>>(
            xt, agt, hb, t ? 6 : 4, 6, pw_gat, gates_b,
            hprev, nullptr, nullptr, rhb, updb);
        // cand: Cin=[x|agg|rh], Cout=64 -> out[t] fp32 + hb f16
        conv_mfma_k<EPI_CAND><<<dim3(11,13,2), dim3(512), 0, stream>>>(
            xt, agt, rhb, t ? 6 : 4, 6, pw_can, can_b,
            hprev, updb, out + (size_t)t*CHW, hb, nullptr);
    }
}